// Round 1
// baseline (682.342 us; speedup 1.0000x reference)
//
#include <hip/hip_runtime.h>
#include <hip/hip_bf16.h>
#include <math.h>

#define N_NODES 100000
#define N_EDGES 3200000
#define IN_F 256
#define OUT_F 64
#define LRELU_SLOPE 0.2f

#define NB 1563                         // buckets of 64 src nodes
#define NREP 32                         // replica counters (keyed blockIdx&31)
#define NC (NB * NREP)                  // 50016
#define SCAN_T 1024
#define SCAN_PER ((NC + SCAN_T - 1) / SCAN_T)   // 49
#define CAP 3072                        // per-chunk LDS edge capacity
#define XPITCH 264                      // LDS row pitch in bf16 (2-way banks)

typedef __attribute__((ext_vector_type(8))) short bf16x8;
typedef __attribute__((ext_vector_type(4))) float f32x4;

// ---------------------------------------------------------------------------
// K0: W (256x64 fp32) -> wt (64x256 bf16, transposed). 64 blocks x 256 thr.
// ---------------------------------------------------------------------------
__global__ __launch_bounds__(256) void wt_kernel(
    const float* __restrict__ W, __hip_bfloat16* __restrict__ wt) {
  wt[blockIdx.x * 256 + threadIdx.x] =
      __float2bfloat16(W[threadIdx.x * 64 + blockIdx.x]);
}

// ---------------------------------------------------------------------------
// K1: h = X @ W via bf16 MFMA 16x16x32, fused s_src = h@a[:64],
// s_dst = h@a[64:]. 64 rows/block, 4 waves; wave w owns rows [16w,16w+16).
// X staged fp32->bf16 in LDS (pitch 264: frag reads ~2-way = free);
// B-frags read 16B from pre-transposed wt (L1-resident, 32 KB).
// A: m=lane&15, k=quad*8+j (m120); C/D: col=lane&15, row=quad*4+reg (m89).
// ---------------------------------------------------------------------------
__global__ __launch_bounds__(256) void gemm_h_kernel(
    const float* __restrict__ in, const __hip_bfloat16* __restrict__ wt,
    const float* __restrict__ a, __hip_bfloat16* __restrict__ h,
    float* __restrict__ s_src, float* __restrict__ s_dst) {
  __shared__ __hip_bfloat16 xl[64 * XPITCH];    // 33792 B
  const int tid = threadIdx.x;
  const int r0 = blockIdx.x * 64;

  // stage X: 64 rows x 256 k, fp32 -> bf16, b64 chunks of 4 k
#pragma unroll
  for (int i = 0; i < 16; ++i) {
    const int e = i * 256 + tid;        // e in [0,4096)
    const int row = e >> 6, kc = e & 63;
    const int grow = r0 + row;
    float4 v = make_float4(0.f, 0.f, 0.f, 0.f);
    if (grow < N_NODES)
      v = *(const float4*)&in[(size_t)grow * IN_F + kc * 4];
    __hip_bfloat16 b4[4] = {__float2bfloat16(v.x), __float2bfloat16(v.y),
                            __float2bfloat16(v.z), __float2bfloat16(v.w)};
    *(uint2*)&xl[row * XPITCH + kc * 4] = *(uint2*)b4;
  }
  __syncthreads();

  const int w = tid >> 6, lane = tid & 63;
  const int lm = lane & 15, lg = lane >> 4;

  f32x4 acc[4];
#pragma unroll
  for (int ct = 0; ct < 4; ++ct) acc[ct] = (f32x4){0.f, 0.f, 0.f, 0.f};

  const __hip_bfloat16* xbase = &xl[(w * 16 + lm) * XPITCH + lg * 8];
  const __hip_bfloat16* wbase = &wt[(size_t)lm * IN_F + lg * 8];

#pragma unroll
  for (int kt = 0; kt < 8; ++kt) {
    bf16x8 af = *(const bf16x8*)(xbase + kt * 32);
#pragma unroll
    for (int ct = 0; ct < 4; ++ct) {
      bf16x8 bfr = *(const bf16x8*)(wbase + (size_t)ct * 16 * IN_F + kt * 32);
      acc[ct] = __builtin_amdgcn_mfma_f32_16x16x32_bf16(af, bfr, acc[ct],
                                                        0, 0, 0);
    }
  }

  // epilogue: h store (bf16) + per-row s reductions over the 16-lane quad grp
  float as[4], ad[4];
#pragma unroll
  for (int ct = 0; ct < 4; ++ct) {
    as[ct] = a[ct * 16 + lm];
    ad[ct] = a[OUT_F + ct * 16 + lm];
  }
#pragma unroll
  for (int reg = 0; reg < 4; ++reg) {
    const int row = r0 + w * 16 + lg * 4 + reg;
    float vs = 0.f, vd = 0.f;
    if (row < N_NODES) {
#pragma unroll
      for (int ct = 0; ct < 4; ++ct) {
        const float v = acc[ct][reg];
        h[(size_t)row * OUT_F + ct * 16 + lm] = __float2bfloat16(v);
        vs += v * as[ct];
        vd += v * ad[ct];
      }
    }
#pragma unroll
    for (int m = 1; m < 16; m <<= 1) {    // reduce within quad group
      vs += __shfl_xor(vs, m);
      vd += __shfl_xor(vd, m);
    }
    if (lm == 0 && row < N_NODES) {
      s_src[row] = vs;
      s_dst[row] = vd;
    }
  }
}

// ---------------------------------------------------------------------------
// K2: bucket histogram, int4 reads (4 edges/thread), 32 replicas
// replica-major: slot = (blockIdx&31)*NB + bucket. Grid must match K4.
// ---------------------------------------------------------------------------
__global__ __launch_bounds__(256) void bucket_hist_kernel(
    const int4* __restrict__ src4, int* __restrict__ bctr) {
  const int t = blockIdx.x * 256 + threadIdx.x;
  const int4 s = src4[t];
  int* r = bctr + (blockIdx.x & 31) * NB;
  atomicAdd(&r[s.x >> 6], 1);
  atomicAdd(&r[s.y >> 6], 1);
  atomicAdd(&r[s.z >> 6], 1);
  atomicAdd(&r[s.w >> 6], 1);
}

// ---------------------------------------------------------------------------
// K3: single-block exclusive scan over ordinals o = bucket*32 + replica
// (slot (o&31)*NB + (o>>5)), in place -> scatter cursors + bstart[NB+1].
// ---------------------------------------------------------------------------
__global__ __launch_bounds__(SCAN_T) void bucket_scan_kernel(
    int* __restrict__ bctr, int* __restrict__ bstart) {
  __shared__ int ts[SCAN_T];
  const int t = threadIdx.x;
  int local[SCAN_PER];
  int sum = 0;
#pragma unroll
  for (int k = 0; k < SCAN_PER; ++k) {
    const int o = t * SCAN_PER + k;
    int v = 0;
    if (o < NC) v = bctr[(o & 31) * NB + (o >> 5)];
    local[k] = sum;
    sum += v;
  }
  ts[t] = sum;
  __syncthreads();
  for (int off = 1; off < SCAN_T; off <<= 1) {
    int tv = (t >= off) ? ts[t - off] : 0;
    __syncthreads();
    ts[t] += tv;
    __syncthreads();
  }
  const int texcl = (t > 0) ? ts[t - 1] : 0;
#pragma unroll
  for (int k = 0; k < SCAN_PER; ++k) {
    const int o = t * SCAN_PER + k;
    if (o < NC) {
      const int excl = texcl + local[k];
      bctr[(o & 31) * NB + (o >> 5)] = excl;
      if ((o & 31) == 0) bstart[o >> 5] = excl;
    }
  }
  if (t == 0) bstart[NB] = N_EDGES;
}

// ---------------------------------------------------------------------------
// K4: bucket-major partition, int4 reads, replica = blockIdx&31 (same
// mapping as K2 -> sub-segment sizes match counts by construction).
// ---------------------------------------------------------------------------
__global__ __launch_bounds__(256) void bucket_scatter_kernel(
    const int4* __restrict__ src4, const int4* __restrict__ dst4,
    int* __restrict__ bctr, unsigned int* __restrict__ staged) {
  const int t = blockIdx.x * 256 + threadIdx.x;
  const int4 s = src4[t];
  const int4 d = dst4[t];
  int* r = bctr + (blockIdx.x & 31) * NB;
  int p;
  p = atomicAdd(&r[s.x >> 6], 1);
  staged[p] = ((unsigned)(s.x & 63) << 17) | (unsigned)d.x;
  p = atomicAdd(&r[s.y >> 6], 1);
  staged[p] = ((unsigned)(s.y & 63) << 17) | (unsigned)d.y;
  p = atomicAdd(&r[s.z >> 6], 1);
  staged[p] = ((unsigned)(s.z & 63) << 17) | (unsigned)d.z;
  p = atomicAdd(&r[s.w >> 6], 1);
  staged[p] = ((unsigned)(s.w & 63) << 17) | (unsigned)d.w;
}

// ---------------------------------------------------------------------------
// K5: one block per bucket. LDS counting sort by local src (ee computed
// once per edge), then register accumulate: wave owns 16 nodes, 4-edge
// batched bf16 gathers. eds packed as uint2 {dst, ee} -> single b64 op.
// ---------------------------------------------------------------------------
__global__ __launch_bounds__(256) void sort_aggregate_kernel(
    const int* __restrict__ bstart, const unsigned int* __restrict__ staged,
    const float* __restrict__ s_src, const float* __restrict__ s_dst,
    const __hip_bfloat16* __restrict__ h, float* __restrict__ out) {
  __shared__ uint2 eds[CAP];            // 24 KB
  __shared__ float ssrc[64];
  __shared__ int lcnt[64];
  __shared__ int lstart[65];
  __shared__ int lcur[64];

  const int b = blockIdx.x;
  const int tid = threadIdx.x;
  const int lane = tid & 63;
  const int wv = tid >> 6;
  const int node0 = b << 6;

  if (tid < 64)
    ssrc[tid] = (node0 + tid < N_NODES) ? s_src[node0 + tid] : 0.f;

  const int e0 = bstart[b];
  const int e1 = bstart[b + 1];

  float acc[16], rsn[16];
#pragma unroll
  for (int j = 0; j < 16; ++j) { acc[j] = 0.f; rsn[j] = 0.f; }

  for (int c0 = e0; c0 < e1; c0 += CAP) {
    const int cc = min(CAP, e1 - c0);
    __syncthreads();
    if (tid < 64) lcnt[tid] = 0;
    __syncthreads();

    // phase A: histogram of local src
    for (int i = tid; i < cc; i += 256)
      atomicAdd(&lcnt[staged[c0 + i] >> 17], 1);
    __syncthreads();

    // wave-0 scan of the 64 counters
    if (tid < 64) {
      int v = lcnt[tid];
#pragma unroll
      for (int off = 1; off < 64; off <<= 1) {
        int tv = __shfl_up(v, off);
        if (lane >= off) v += tv;
      }
      lstart[tid + 1] = v;
      if (tid == 0) lstart[0] = 0;
      lcur[tid] = v - lcnt[tid];
    }
    __syncthreads();

    // phase B: ee once per edge, scatter sorted into LDS (packed b64)
    for (int i = tid; i < cc; i += 256) {
      const unsigned pk = staged[c0 + i];
      const int ls = (int)(pk >> 17);
      const int d = (int)(pk & 0x1FFFFu);
      const float sc = ssrc[ls] + s_dst[d];
      const float lr = sc > 0.f ? sc : LRELU_SLOPE * sc;
      const float ev = __expf(-lr);
      const int p = atomicAdd(&lcur[ls], 1);
      eds[p] = make_uint2((unsigned)d, __float_as_uint(ev));
    }
    __syncthreads();

    // phase C: wave wv accumulates its 16 nodes in registers
#pragma unroll
    for (int j = 0; j < 16; ++j) {
      const int n = wv + 4 * j;
      const int iend = lstart[n + 1];
      int i = lstart[n];
      float p0 = 0.f, p1 = 0.f, rv = 0.f;
      for (; i + 4 <= iend; i += 4) {
        const uint2 q0 = eds[i + 0], q1 = eds[i + 1];
        const uint2 q2 = eds[i + 2], q3 = eds[i + 3];
        const float v0 = __uint_as_float(q0.y), v1 = __uint_as_float(q1.y);
        const float v2 = __uint_as_float(q2.y), v3 = __uint_as_float(q3.y);
        const float h0 = __bfloat162float(h[(size_t)q0.x * OUT_F + lane]);
        const float h1 = __bfloat162float(h[(size_t)q1.x * OUT_F + lane]);
        const float h2 = __bfloat162float(h[(size_t)q2.x * OUT_F + lane]);
        const float h3 = __bfloat162float(h[(size_t)q3.x * OUT_F + lane]);
        p0 += v0 * h0 + v2 * h2;
        p1 += v1 * h1 + v3 * h3;
        rv += (v0 + v1) + (v2 + v3);
      }
      for (; i < iend; ++i) {
        const uint2 q0 = eds[i];
        const float v0 = __uint_as_float(q0.y);
        p0 += v0 * __bfloat162float(h[(size_t)q0.x * OUT_F + lane]);
        rv += v0;
      }
      acc[j] += p0 + p1;
      rsn[j] += rv;
    }
  }

  // epilogue: out = elu(acc / rowsum)
#pragma unroll
  for (int j = 0; j < 16; ++j) {
    const int node = node0 + wv + 4 * j;
    if (node < N_NODES) {
      const float v = acc[j] / rsn[j];
      out[(size_t)node * OUT_F + lane] = v > 0.f ? v : expm1f(v);
    }
  }
}

extern "C" void kernel_launch(void* const* d_in, const int* in_sizes, int n_in,
                              void* d_out, int out_size, void* d_ws, size_t ws_size,
                              hipStream_t stream) {
  const float* in = (const float*)d_in[0];
  const int* edge = (const int*)d_in[1];
  const float* W = (const float*)d_in[2];
  const float* a = (const float*)d_in[3];
  float* out = (float*)d_out;

  const int4* src4 = (const int4*)edge;
  const int4* dst4 = (const int4*)(edge + N_EDGES);

  // workspace: 12.8 + 0.4 + 0.4 + 12.8 + 0.2 + 0.006 + 0.03 MB = 26.7 MB
  char* p = (char*)d_ws;
  __hip_bfloat16* h = (__hip_bfloat16*)p;  p += (size_t)N_NODES * OUT_F * 2;
  float* s_src = (float*)p;                p += (size_t)N_NODES * 4;
  float* s_dst = (float*)p;                p += (size_t)N_NODES * 4;
  unsigned int* staged = (unsigned int*)p; p += (size_t)N_EDGES * 4;
  int* bctr = (int*)p;                     p += (size_t)NC * 4;
  int* bstart = (int*)p;                   p += (size_t)(NB + 1) * 4 + 12;
  __hip_bfloat16* wt = (__hip_bfloat16*)p; p += (size_t)OUT_F * IN_F * 2;

  hipMemsetAsync(bctr, 0, (size_t)NC * 4, stream);

  wt_kernel<<<OUT_F, 256, 0, stream>>>(W, wt);
  gemm_h_kernel<<<(N_NODES + 63) / 64, 256, 0, stream>>>(in, wt, a, h, s_src,
                                                         s_dst);
  bucket_hist_kernel<<<N_EDGES / 1024, 256, 0, stream>>>(src4, bctr);
  bucket_scan_kernel<<<1, SCAN_T, 0, stream>>>(bctr, bstart);
  bucket_scatter_kernel<<<N_EDGES / 1024, 256, 0, stream>>>(src4, dst4, bctr,
                                                            staged);
  sort_aggregate_kernel<<<NB, 256, 0, stream>>>(bstart, staged, s_src, s_dst,
                                                h, out);
}